// Round 1
// baseline (442.258 us; speedup 1.0000x reference)
//
#include <hip/hip_runtime.h>
#include <math.h>

#define BB 4
#define TT 128
#define DD 768
#define HD 770
#define LL 40
#define TP1 129

// ws layout (floats)
#define P_OFF   0
#define QT_OFF  (BB*TT*HD)
#define ACC_OFF (2*BB*TT*HD)
#define LSE_OFF (2*BB*TT*HD + BB*LL)

// -------- zero the exp-sum accumulator (ws is poisoned each call) --------
__global__ __launch_bounds__(256) void kZ(float* __restrict__ accum) {
    if (threadIdx.x < BB*LL) accum[threadIdx.x] = 0.0f;
}

// -------- kA: P[b][t][h] = vecs[b,t,:]@W1[0:D,h] + b1[h]
//              QT[b][h][t] = vecs[b,t,:]@W1[D:2D,h]
// grid (64 t-tiles of 8, 4 h-chunks of 256), block 256
__global__ __launch_bounds__(256) void kA(const float* __restrict__ hidden,
                                          const float* __restrict__ W1,
                                          const float* __restrict__ b1,
                                          float* __restrict__ P,
                                          float* __restrict__ QT) {
    __shared__ float xs[DD * 8];   // xs[k][t], stride 8 floats (16B-aligned rows)
    const int tid = threadIdx.x;
    const int tile = blockIdx.x;        // 0..63
    const int t0 = tile * 8;            // flat (b*T + t) start
    const int b  = t0 >> 7;
    const int tb = t0 & 127;

    // stage 8 token vectors, coalesced along k
    for (int idx = tid; idx < 8 * DD; idx += 256) {
        int tloc = idx / DD;
        int k    = idx - tloc * DD;
        xs[k * 8 + tloc] = hidden[(size_t)(b * TP1 + 1 + tb + tloc) * DD + k];
    }
    __syncthreads();

    const int h = blockIdx.y * 256 + tid;
    if (h >= HD) return;

    float accP[8], accQ[8];
    #pragma unroll
    for (int t = 0; t < 8; ++t) { accP[t] = 0.f; accQ[t] = 0.f; }

    const float* __restrict__ Wa = W1 + h;
    const float* __restrict__ Wb = W1 + (size_t)DD * HD + h;

    #pragma unroll 4
    for (int k = 0; k < DD; ++k) {
        const float4* x4 = (const float4*)(xs + k * 8);
        float4 xa = x4[0];
        float4 xb = x4[1];
        float wa = Wa[(size_t)k * HD];
        float wb = Wb[(size_t)k * HD];
        accP[0] += xa.x * wa; accP[1] += xa.y * wa;
        accP[2] += xa.z * wa; accP[3] += xa.w * wa;
        accP[4] += xb.x * wa; accP[5] += xb.y * wa;
        accP[6] += xb.z * wa; accP[7] += xb.w * wa;
        accQ[0] += xa.x * wb; accQ[1] += xa.y * wb;
        accQ[2] += xa.z * wb; accQ[3] += xa.w * wb;
        accQ[4] += xb.x * wb; accQ[5] += xb.y * wb;
        accQ[6] += xb.z * wb; accQ[7] += xb.w * wb;
    }

    const float pb = b1[h];
    #pragma unroll
    for (int t = 0; t < 8; ++t)
        P[(size_t)(b * TT + tb + t) * HD + h] = accP[t] + pb;

    float4 q0 = make_float4(accQ[0], accQ[1], accQ[2], accQ[3]);
    float4 q1 = make_float4(accQ[4], accQ[5], accQ[6], accQ[7]);
    float* qdst = QT + (size_t)b * HD * TT + (size_t)h * TT + tb;
    ((float4*)qdst)[0] = q0;
    ((float4*)qdst)[1] = q1;
}

// -------- kB: out[b,pos,l] = mask ? relu(P+Q+ind*w1L) @ W2[:,l] + b2[l] : 0
// one wave = 64 consecutive j (i fixed), 20 of 40 outputs (l-split x2)
// grid 512 blocks x 256 threads = 2048 waves
__global__ __launch_bounds__(256) void kB(const float* __restrict__ P,
                                          const float* __restrict__ QT,
                                          const float* __restrict__ W1,
                                          const float* __restrict__ W2,
                                          const float* __restrict__ b2,
                                          const int* __restrict__ spans,
                                          const int* __restrict__ avail,
                                          float* __restrict__ out) {
    const int tid  = threadIdx.x;
    const int gw   = blockIdx.x * 4 + (tid >> 6);   // global wave id, 0..2047
    const int lane = tid & 63;
    const int lsplit = gw & 1;
    const int tile = gw >> 1;                        // 0..1023
    const int b   = tile >> 8;
    const int rem = tile & 255;
    const int i   = rem >> 1;
    const int j0  = (rem & 1) << 6;
    const int j   = j0 + lane;
    const int l0  = lsplit * 20;

    const int start = spans[b * 2];
    const int end   = spans[b * 2 + 1];
    const bool isfull = (i == start) && (j == end);
    const bool inside = (start <= i) && (i <= j) && (j <= end) && !isfull;
    const float ind = isfull ? 2.0f : (inside ? 1.0f : 0.0f);
    const bool msk = avail[i * TT + j] >= 1;

    const float* __restrict__ Pi  = P + (size_t)(b * TT + i) * HD;
    const float* __restrict__ Qc  = QT + (size_t)b * HD * TT + j;
    const float* __restrict__ w1L = W1 + (size_t)2 * DD * HD;   // row 1536

    float acc[20];
    #pragma unroll
    for (int l = 0; l < 20; ++l) acc[l] = 0.f;

    for (int hh = 0; hh < HD; ++hh) {
        float qv = Qc[(size_t)hh * TT];            // coalesced across lanes
        float sv = Pi[hh] + qv + ind * w1L[hh];    // Pi/w1L wave-uniform
        sv = fmaxf(sv, 0.0f);
        const float4* w4 = (const float4*)(W2 + (size_t)hh * LL + l0);
        #pragma unroll
        for (int g = 0; g < 5; ++g) {
            float4 w = w4[g];                      // wave-uniform -> s_load
            acc[4*g + 0] += sv * w.x;
            acc[4*g + 1] += sv * w.y;
            acc[4*g + 2] += sv * w.z;
            acc[4*g + 3] += sv * w.w;
        }
    }

    const int pos = i * TT + j;
    float* op = out + ((size_t)b * (TT * TT) + pos) * LL + l0;
    #pragma unroll
    for (int g = 0; g < 5; ++g) {
        float4 v;
        v.x = msk ? acc[4*g + 0] + b2[l0 + 4*g + 0] : 0.0f;
        v.y = msk ? acc[4*g + 1] + b2[l0 + 4*g + 1] : 0.0f;
        v.z = msk ? acc[4*g + 2] + b2[l0 + 4*g + 2] : 0.0f;
        v.w = msk ? acc[4*g + 3] + b2[l0 + 4*g + 3] : 0.0f;
        ((float4*)op)[g] = v;
    }
}

// -------- kC: partial exp-sums over positions -> accum[b*40+l] (atomic)
// grid (16 p-chunks, B), 320 threads
__global__ __launch_bounds__(320) void kC(const float* __restrict__ out,
                                          float* __restrict__ accum) {
    const int pc = blockIdx.x;
    const int b  = blockIdx.y;
    const int tid = threadIdx.x;
    const int l    = tid % 40;
    const int slot = tid / 40;   // 0..7

    const float* base = out + ((size_t)b * (TT * TT) + (size_t)pc * 1024) * LL;
    float s = 0.f;
    for (int k = 0; k < 128; ++k) {
        s += expf(base[(size_t)(slot + 8 * k) * LL + l]);
    }
    __shared__ float red[320];
    red[tid] = s;
    __syncthreads();
    if (tid < 40) {
        float t = 0.f;
        #pragma unroll
        for (int q = 0; q < 8; ++q) t += red[tid + 40 * q];
        atomicAdd(&accum[b * LL + tid], t);
    }
}

// -------- kC2: lse = log(sum) --------
__global__ __launch_bounds__(192) void kC2(const float* __restrict__ accum,
                                           float* __restrict__ lse) {
    int t = threadIdx.x;
    if (t < BB * LL) lse[t] = logf(accum[t]);
}

// -------- kD: out -= lse[b,l] (elementwise, float4) --------
__global__ __launch_bounds__(256) void kD(float* __restrict__ out,
                                          const float* __restrict__ lse) {
    const int idx = blockIdx.x * 256 + threadIdx.x;   // float4 index, < 655360
    const int e = idx * 4;
    const int b = e / (TT * TT * LL);
    const int l = e % LL;                             // 40%4==0: stays in-row
    float4 v = ((float4*)out)[idx];
    const float* ls = lse + b * LL + l;
    v.x -= ls[0]; v.y -= ls[1]; v.z -= ls[2]; v.w -= ls[3];
    ((float4*)out)[idx] = v;
}

extern "C" void kernel_launch(void* const* d_in, const int* in_sizes, int n_in,
                              void* d_out, int out_size, void* d_ws, size_t ws_size,
                              hipStream_t stream) {
    const float* hidden = (const float*)d_in[0];
    const float* W1     = (const float*)d_in[1];
    const float* b1     = (const float*)d_in[2];
    const float* W2     = (const float*)d_in[3];
    const float* b2     = (const float*)d_in[4];
    const int*   spans  = (const int*)d_in[5];
    const int*   avail  = (const int*)d_in[6];
    float* out = (float*)d_out;
    float* ws  = (float*)d_ws;

    float* P     = ws + P_OFF;
    float* QT    = ws + QT_OFF;
    float* accum = ws + ACC_OFF;
    float* lse   = ws + LSE_OFF;

    kZ <<<dim3(1),        dim3(256), 0, stream>>>(accum);
    kA <<<dim3(64, 4),    dim3(256), 0, stream>>>(hidden, W1, b1, P, QT);
    kB <<<dim3(512),      dim3(256), 0, stream>>>(P, QT, W1, W2, b2, spans, avail, out);
    kC <<<dim3(16, BB),   dim3(320), 0, stream>>>(out, accum);
    kC2<<<dim3(1),        dim3(192), 0, stream>>>(accum, lse);
    kD <<<dim3(2560),     dim3(256), 0, stream>>>(out, lse);
}

// Round 2
// 350.810 us; speedup vs baseline: 1.2607x; 1.2607x over previous
//
#include <hip/hip_runtime.h>
#include <math.h>

#define BB 4
#define TT 128
#define DD 768
#define HD 770
#define LL 40
#define TP1 129
#define CH 64

// ws layout (floats)
#define P_OFF   0
#define QT_OFF  (BB*TT*HD)
#define ACC_OFF (2*BB*TT*HD)
#define LSE_OFF (2*BB*TT*HD + BB*LL)

// -------- zero the exp-sum accumulator (ws is poisoned each call) --------
__global__ __launch_bounds__(256) void kZ(float* __restrict__ accum) {
    if (threadIdx.x < BB*LL) accum[threadIdx.x] = 0.0f;
}

// -------- kA: P[b][t][h] = vecs[b,t,:]@W1[0:D,h] + b1[h]
//              QT[b][h][t] = vecs[b,t,:]@W1[D:2D,h]
// grid (128 t-tiles of 4, 4 h-chunks of 256), block 256 -> 512 blocks
__global__ __launch_bounds__(256) void kA(const float* __restrict__ hidden,
                                          const float* __restrict__ W1,
                                          const float* __restrict__ b1,
                                          float* __restrict__ P,
                                          float* __restrict__ QT) {
    __shared__ float xs[DD * 4];   // xs[k][t], stride 4 floats (16B rows)
    const int tid = threadIdx.x;
    const int tile = blockIdx.x;        // 0..127
    const int t0 = tile * 4;            // flat (b*T + t) start
    const int b  = t0 >> 7;
    const int tb = t0 & 127;

    // stage 4 token vectors, coalesced along k
    #pragma unroll
    for (int r = 0; r < 4; ++r)
        for (int k = tid; k < DD; k += 256)
            xs[k * 4 + r] = hidden[(size_t)(b * TP1 + 1 + tb + r) * DD + k];
    __syncthreads();

    const int h = blockIdx.y * 256 + tid;
    if (h >= HD) return;

    float accP[4], accQ[4];
    #pragma unroll
    for (int t = 0; t < 4; ++t) { accP[t] = 0.f; accQ[t] = 0.f; }

    const float* __restrict__ Wa = W1 + h;
    const float* __restrict__ Wb = W1 + (size_t)DD * HD + h;

    #pragma unroll 8
    for (int k = 0; k < DD; ++k) {
        float4 xa = ((const float4*)(xs + k * 4))[0];
        float wa = Wa[(size_t)k * HD];
        float wb = Wb[(size_t)k * HD];
        accP[0] += xa.x * wa; accP[1] += xa.y * wa;
        accP[2] += xa.z * wa; accP[3] += xa.w * wa;
        accQ[0] += xa.x * wb; accQ[1] += xa.y * wb;
        accQ[2] += xa.z * wb; accQ[3] += xa.w * wb;
    }

    const float pb = b1[h];
    #pragma unroll
    for (int t = 0; t < 4; ++t)
        P[(size_t)(b * TT + tb + t) * HD + h] = accP[t] + pb;

    float4 q0 = make_float4(accQ[0], accQ[1], accQ[2], accQ[3]);
    float* qdst = QT + (size_t)b * HD * TT + (size_t)h * TT + tb;
    ((float4*)qdst)[0] = q0;
}

// -------- kB: out[b,pos,l] = mask ? relu(P+Q+ind*w1L) @ W2[:,l] + b2[l] : 0
// block = 256 thr = 4 waves: (i_local 0..1) x (l-half 0..1), shared (b, i-pair, j-half)
// grid (j-half 2, i-pair 64, b 4) = 512 blocks. All inner-loop reads from LDS.
__global__ __launch_bounds__(256) void kB(const float* __restrict__ P,
                                          const float* __restrict__ QT,
                                          const float* __restrict__ W1,
                                          const float* __restrict__ W2,
                                          const float* __restrict__ b2,
                                          const int* __restrict__ spans,
                                          const int* __restrict__ avail,
                                          float* __restrict__ out) {
    __shared__ float qs[CH * 64];    // 16 KB  qs[hl][j]
    __shared__ float w2s[CH * 40];   // 10 KB  w2s[hl][l]
    __shared__ float ps[2 * CH];     // ps[il][hl]
    __shared__ float ws1[CH];        // w1 last row chunk

    const int jh = blockIdx.x;
    const int ip = blockIdx.y;
    const int b  = blockIdx.z;
    const int tid  = threadIdx.x;
    const int wave = tid >> 6;
    const int lane = tid & 63;
    const int il = wave & 1;
    const int lh = wave >> 1;
    const int i  = ip * 2 + il;
    const int j0 = jh * 64;
    const int j  = j0 + lane;
    const int l0 = lh * 20;

    const int start = spans[b * 2];
    const int end   = spans[b * 2 + 1];
    const bool isfull = (i == start) && (j == end);
    const bool inside = (start <= i) && (i <= j) && (j <= end) && !isfull;
    const float ind = isfull ? 2.0f : (inside ? 1.0f : 0.0f);
    const bool msk = avail[i * TT + j] >= 1;

    const float* __restrict__ QTb = QT + (size_t)b * HD * TT;
    const float* __restrict__ Pb  = P + (size_t)b * TT * HD;
    const float* __restrict__ w1L = W1 + (size_t)2 * DD * HD;   // row 1536

    float acc[20];
    #pragma unroll
    for (int l = 0; l < 20; ++l) acc[l] = 0.f;

    // 12 full chunks of 64
    for (int c = 0; c < 12; ++c) {
        const int h0 = c * CH;
        __syncthreads();
        #pragma unroll
        for (int r = wave; r < CH; r += 4)
            qs[r * 64 + lane] = QTb[(size_t)(h0 + r) * TT + j0 + lane];
        #pragma unroll
        for (int r = wave; r < CH; r += 4)
            if (lane < 40)
                w2s[r * 40 + lane] = W2[(size_t)(h0 + r) * LL + lane];
        if (wave < 2)
            ps[wave * CH + lane] = Pb[(size_t)(ip * 2 + wave) * HD + h0 + lane];
        if (wave == 2)
            ws1[lane] = w1L[h0 + lane];
        __syncthreads();

        #pragma unroll 8
        for (int hl = 0; hl < CH; ++hl) {
            float sv = ps[il * CH + hl] + qs[hl * 64 + lane] + ind * ws1[hl];
            sv = fmaxf(sv, 0.0f);
            const float4* w4 = (const float4*)(w2s + hl * 40 + l0);
            float4 wv0 = w4[0], wv1 = w4[1], wv2 = w4[2], wv3 = w4[3], wv4 = w4[4];
            acc[0]  += sv * wv0.x; acc[1]  += sv * wv0.y; acc[2]  += sv * wv0.z; acc[3]  += sv * wv0.w;
            acc[4]  += sv * wv1.x; acc[5]  += sv * wv1.y; acc[6]  += sv * wv1.z; acc[7]  += sv * wv1.w;
            acc[8]  += sv * wv2.x; acc[9]  += sv * wv2.y; acc[10] += sv * wv2.z; acc[11] += sv * wv2.w;
            acc[12] += sv * wv3.x; acc[13] += sv * wv3.y; acc[14] += sv * wv3.z; acc[15] += sv * wv3.w;
            acc[16] += sv * wv4.x; acc[17] += sv * wv4.y; acc[18] += sv * wv4.z; acc[19] += sv * wv4.w;
        }
    }

    // tail: h0 = 768, 2 rows
    {
        __syncthreads();
        if (wave < 2)
            qs[wave * 64 + lane] = QTb[(size_t)(768 + wave) * TT + j0 + lane];
        if (wave == 2 && lane < 40)
            w2s[lane] = W2[(size_t)768 * LL + lane];
        if (wave == 3 && lane < 40)
            w2s[40 + lane] = W2[(size_t)769 * LL + lane];
        if (tid < 4)
            ps[tid] = Pb[(size_t)(ip * 2 + (tid >> 1)) * HD + 768 + (tid & 1)];
        if (tid >= 4 && tid < 6)
            ws1[tid - 4] = w1L[768 + tid - 4];
        __syncthreads();

        #pragma unroll
        for (int hl = 0; hl < 2; ++hl) {
            float sv = ps[il * 2 + hl] + qs[hl * 64 + lane] + ind * ws1[hl];
            sv = fmaxf(sv, 0.0f);
            const float4* w4 = (const float4*)(w2s + hl * 40 + l0);
            float4 wv0 = w4[0], wv1 = w4[1], wv2 = w4[2], wv3 = w4[3], wv4 = w4[4];
            acc[0]  += sv * wv0.x; acc[1]  += sv * wv0.y; acc[2]  += sv * wv0.z; acc[3]  += sv * wv0.w;
            acc[4]  += sv * wv1.x; acc[5]  += sv * wv1.y; acc[6]  += sv * wv1.z; acc[7]  += sv * wv1.w;
            acc[8]  += sv * wv2.x; acc[9]  += sv * wv2.y; acc[10] += sv * wv2.z; acc[11] += sv * wv2.w;
            acc[12] += sv * wv3.x; acc[13] += sv * wv3.y; acc[14] += sv * wv3.z; acc[15] += sv * wv3.w;
            acc[16] += sv * wv4.x; acc[17] += sv * wv4.y; acc[18] += sv * wv4.z; acc[19] += sv * wv4.w;
        }
    }

    const int pos = i * TT + j;
    float* op = out + ((size_t)b * (TT * TT) + pos) * LL + l0;
    #pragma unroll
    for (int g = 0; g < 5; ++g) {
        float4 v;
        v.x = msk ? acc[4*g + 0] + b2[l0 + 4*g + 0] : 0.0f;
        v.y = msk ? acc[4*g + 1] + b2[l0 + 4*g + 1] : 0.0f;
        v.z = msk ? acc[4*g + 2] + b2[l0 + 4*g + 2] : 0.0f;
        v.w = msk ? acc[4*g + 3] + b2[l0 + 4*g + 3] : 0.0f;
        ((float4*)op)[g] = v;
    }
}

// -------- kC: partial exp-sums over positions -> accum[b*40+l] (atomic)
// grid (64 p-chunks, B), 320 threads, 32 serial iters each
__global__ __launch_bounds__(320) void kC(const float* __restrict__ out,
                                          float* __restrict__ accum) {
    const int pc = blockIdx.x;
    const int b  = blockIdx.y;
    const int tid = threadIdx.x;

    const float* base = out + ((size_t)b * (TT * TT) + (size_t)pc * 256) * LL;
    float s = 0.f;
    #pragma unroll 4
    for (int k = 0; k < 32; ++k) {
        s += expf(base[(size_t)k * 320 + tid]);
    }
    __shared__ float red[320];
    red[tid] = s;
    __syncthreads();
    if (tid < 40) {
        float t = 0.f;
        #pragma unroll
        for (int q = 0; q < 8; ++q) t += red[tid + 40 * q];
        atomicAdd(&accum[b * LL + tid], t);
    }
}

// -------- kC2: lse = log(sum) --------
__global__ __launch_bounds__(192) void kC2(const float* __restrict__ accum,
                                           float* __restrict__ lse) {
    int t = threadIdx.x;
    if (t < BB * LL) lse[t] = logf(accum[t]);
}

// -------- kD: out -= lse[b,l] (elementwise, float4) --------
__global__ __launch_bounds__(256) void kD(float* __restrict__ out,
                                          const float* __restrict__ lse) {
    const int idx = blockIdx.x * 256 + threadIdx.x;   // float4 index, < 655360
    const int e = idx * 4;
    const int b = e / (TT * TT * LL);
    const int l = e % LL;                             // 40%4==0: stays in-row
    float4 v = ((float4*)out)[idx];
    const float* ls = lse + b * LL + l;
    v.x -= ls[0]; v.y -= ls[1]; v.z -= ls[2]; v.w -= ls[3];
    ((float4*)out)[idx] = v;
}

extern "C" void kernel_launch(void* const* d_in, const int* in_sizes, int n_in,
                              void* d_out, int out_size, void* d_ws, size_t ws_size,
                              hipStream_t stream) {
    const float* hidden = (const float*)d_in[0];
    const float* W1     = (const float*)d_in[1];
    const float* b1     = (const float*)d_in[2];
    const float* W2     = (const float*)d_in[3];
    const float* b2     = (const float*)d_in[4];
    const int*   spans  = (const int*)d_in[5];
    const int*   avail  = (const int*)d_in[6];
    float* out = (float*)d_out;
    float* ws  = (float*)d_ws;

    float* P     = ws + P_OFF;
    float* QT    = ws + QT_OFF;
    float* accum = ws + ACC_OFF;
    float* lse   = ws + LSE_OFF;

    kZ <<<dim3(1),          dim3(256), 0, stream>>>(accum);
    kA <<<dim3(128, 4),     dim3(256), 0, stream>>>(hidden, W1, b1, P, QT);
    kB <<<dim3(2, 64, 4),   dim3(256), 0, stream>>>(P, QT, W1, W2, b2, spans, avail, out);
    kC <<<dim3(64, BB),     dim3(320), 0, stream>>>(out, accum);
    kC2<<<dim3(1),          dim3(192), 0, stream>>>(accum, lse);
    kD <<<dim3(2560),       dim3(256), 0, stream>>>(out, lse);
}

// Round 3
// 168.459 us; speedup vs baseline: 2.6253x; 2.0825x over previous
//
#include <hip/hip_runtime.h>
#include <math.h>

#define BB 4
#define TT 128
#define DD 768
#define HD 770
#define HP 800
#define LL 40
#define TP1 129

typedef __attribute__((ext_vector_type(8))) short s16x8;
typedef __attribute__((ext_vector_type(4))) float f32x4;

// ws layout (floats)
#define P_OFF   0
#define Q_OFF   (BB*TT*HP)
#define BF_OFF  (2*BB*TT*HP)            // B-frags: 3*25*64*8 bf16 = 19200 floats-worth
#define ACC_OFF (2*BB*TT*HP + 19200)
#define LSE_OFF (ACC_OFF + BB*LL)

__device__ __forceinline__ unsigned pkbf(float a, float b) {
    unsigned ua = __float_as_uint(a);
    unsigned ub = __float_as_uint(b);
    return ((ua + 0x8000u) >> 16) | ((ub + 0x8000u) & 0xffff0000u);
}

// -------- zero the exp-sum accumulator --------
__global__ __launch_bounds__(256) void kZ(float* __restrict__ accum) {
    if (threadIdx.x < BB*LL) accum[threadIdx.x] = 0.0f;
}

// -------- kW: pre-swizzle W2 -> bf16 B-fragments [nt 0..2][ks 0..24][lane 0..63][8]
// element: k = ks*32 + (lane>>4)*8 + s, l = nt*16 + (lane&15); zero-pad k>=770, l>=40
__global__ __launch_bounds__(256) void kW(const float* __restrict__ W2,
                                          unsigned* __restrict__ Bfrag) {
    int u = blockIdx.x * 256 + threadIdx.x;
    if (u >= 4800) return;
    int nt = u / 1600;
    int rem = u - nt * 1600;
    int ks = rem >> 6;
    int lane = rem & 63;
    int kbase = ks * 32 + ((lane >> 4) << 3);
    int l = nt * 16 + (lane & 15);
    unsigned pk[4];
    #pragma unroll
    for (int sp = 0; sp < 4; ++sp) {
        unsigned w[2];
        #pragma unroll
        for (int e = 0; e < 2; ++e) {
            int k = kbase + 2*sp + e;
            float v = (k < HD && l < LL) ? W2[k * LL + l] : 0.0f;
            unsigned x = __float_as_uint(v);
            w[e] = (x + 0x7fffu + ((x >> 16) & 1u)) >> 16;   // RNE
        }
        pk[sp] = w[0] | (w[1] << 16);
    }
    ((uint4*)Bfrag)[u] = make_uint4(pk[0], pk[1], pk[2], pk[3]);
}

// -------- kA: P[b][t][h]=vecs@W1[:D]+b1 (stride HP), Q[b][t][h]=vecs@W1[D:2D]
// Q rows zero-padded h in [770,800). grid (128 t-tiles of 4, 4 h-chunks of 256)
__global__ __launch_bounds__(256) void kA(const float* __restrict__ hidden,
                                          const float* __restrict__ W1,
                                          const float* __restrict__ b1,
                                          float* __restrict__ P,
                                          float* __restrict__ Q) {
    __shared__ float xs[DD * 4];
    const int tid = threadIdx.x;
    const int t0 = blockIdx.x * 4;
    const int b  = t0 >> 7;
    const int tb = t0 & 127;

    #pragma unroll
    for (int r = 0; r < 4; ++r)
        for (int k = tid; k < DD; k += 256)
            xs[k * 4 + r] = hidden[(size_t)(b * TP1 + 1 + tb + r) * DD + k];
    __syncthreads();

    const int h = blockIdx.y * 256 + tid;
    if (h < HD) {
        float accP[4] = {0.f,0.f,0.f,0.f}, accQ[4] = {0.f,0.f,0.f,0.f};
        const float* __restrict__ Wa = W1 + h;
        const float* __restrict__ Wb = W1 + (size_t)DD * HD + h;
        #pragma unroll 8
        for (int k = 0; k < DD; ++k) {
            float4 xa = ((const float4*)(xs + k * 4))[0];
            float wa = Wa[(size_t)k * HD];
            float wb = Wb[(size_t)k * HD];
            accP[0] += xa.x * wa; accP[1] += xa.y * wa;
            accP[2] += xa.z * wa; accP[3] += xa.w * wa;
            accQ[0] += xa.x * wb; accQ[1] += xa.y * wb;
            accQ[2] += xa.z * wb; accQ[3] += xa.w * wb;
        }
        const float pb = b1[h];
        #pragma unroll
        for (int t = 0; t < 4; ++t) {
            P[(size_t)(b * TT + tb + t) * HP + h] = accP[t] + pb;
            Q[(size_t)(b * TT + tb + t) * HP + h] = accQ[t];
        }
    } else if (h < HP) {
        #pragma unroll
        for (int t = 0; t < 4; ++t)
            Q[(size_t)(b * TT + tb + t) * HP + h] = 0.0f;
    }
}

// -------- kB: MFMA. block=(i,b), 4 waves. M=128(j) N=48(l,pad) K=800(h,pad)
__global__ __launch_bounds__(256) void kB(const float* __restrict__ P,
                                          const float* __restrict__ Q,
                                          const float* __restrict__ W1,
                                          const unsigned* __restrict__ Bfrag,
                                          const float* __restrict__ b2,
                                          const int* __restrict__ spans,
                                          const int* __restrict__ avail,
                                          float* __restrict__ out) {
    __shared__ unsigned Sb[2][128 * 20];   // bf16 S-tile, row = 40 bf16 (32 used)
    __shared__ float var[3 * HP];          // P[i][h] + v*w1L[h], v=0,1,2 (0 for h>=770)
    __shared__ int avi[TT];

    const int i = blockIdx.x;
    const int b = blockIdx.y;
    const int tid = threadIdx.x;
    const int wave = tid >> 6;
    const int lane = tid & 63;

    const int start = spans[b * 2];
    const int end   = spans[b * 2 + 1];

    // S-form role: thread covers (j = tid>>1, h-half hh = (tid&1)*16)
    const int jS = tid >> 1;
    const int hh = (tid & 1) << 4;
    int indS;
    {
        bool isfull = (i == start) && (jS == end);
        bool inside = (start <= i) && (i <= jS) && (jS <= end) && !isfull;
        indS = isfull ? 2 : (inside ? 1 : 0);
    }

    {
        const float* Pi  = P + (size_t)(b * TT + i) * HP;
        const float* w1L = W1 + (size_t)2 * DD * HD;
        for (int h = tid; h < HP; h += 256) {
            float pv = (h < HD) ? Pi[h] : 0.0f;
            float wv = (h < HD) ? w1L[h] : 0.0f;
            var[h]          = pv;
            var[HP + h]     = pv + wv;
            var[2*HP + h]   = pv + wv + wv;
        }
        if (tid < TT) avi[tid] = avail[i * TT + tid];
    }
    __syncthreads();

    const float* Qj = Q + (size_t)(b * TT + jS) * HP;
    const float* vb = var + indS * HP;

    auto form = [&](int c, int p) {
        const int h0 = c * 32 + hh;
        const float4* qp = (const float4*)(Qj + h0);
        float4 q0 = qp[0], q1 = qp[1], q2 = qp[2], q3 = qp[3];
        const float4* vp = (const float4*)(vb + h0);
        float4 v0 = vp[0], v1 = vp[1], v2 = vp[2], v3 = vp[3];
        float s0 = fmaxf(v0.x + q0.x, 0.f), s1 = fmaxf(v0.y + q0.y, 0.f);
        float s2 = fmaxf(v0.z + q0.z, 0.f), s3 = fmaxf(v0.w + q0.w, 0.f);
        float s4 = fmaxf(v1.x + q1.x, 0.f), s5 = fmaxf(v1.y + q1.y, 0.f);
        float s6 = fmaxf(v1.z + q1.z, 0.f), s7 = fmaxf(v1.w + q1.w, 0.f);
        float s8 = fmaxf(v2.x + q2.x, 0.f), s9 = fmaxf(v2.y + q2.y, 0.f);
        float sa = fmaxf(v2.z + q2.z, 0.f), sb_ = fmaxf(v2.w + q2.w, 0.f);
        float sc = fmaxf(v3.x + q3.x, 0.f), sd = fmaxf(v3.y + q3.y, 0.f);
        float se = fmaxf(v3.z + q3.z, 0.f), sf = fmaxf(v3.w + q3.w, 0.f);
        uint4* dst = (uint4*)(&Sb[p][jS * 20 + (hh >> 1)]);
        dst[0] = make_uint4(pkbf(s0,s1), pkbf(s2,s3), pkbf(s4,s5), pkbf(s6,s7));
        dst[1] = make_uint4(pkbf(s8,s9), pkbf(sa,sb_), pkbf(sc,sd), pkbf(se,sf));
    };

    f32x4 acc[2][3];
    #pragma unroll
    for (int mt = 0; mt < 2; ++mt)
        #pragma unroll
        for (int nt = 0; nt < 3; ++nt)
            acc[mt][nt] = (f32x4){0.f, 0.f, 0.f, 0.f};

    form(0, 0);
    __syncthreads();

    const int arow0 = (wave * 32 + (lane & 15)) * 20 + ((lane >> 4) << 2);
    for (int c = 0; c < 25; ++c) {
        const int p = c & 1;
        s16x8 bf0 = *(const s16x8*)(Bfrag + (( 0 + c) * 64 + lane) * 4);
        s16x8 bf1 = *(const s16x8*)(Bfrag + ((25 + c) * 64 + lane) * 4);
        s16x8 bf2 = *(const s16x8*)(Bfrag + ((50 + c) * 64 + lane) * 4);
        s16x8 af0 = *(const s16x8*)(&Sb[p][arow0]);
        s16x8 af1 = *(const s16x8*)(&Sb[p][arow0 + 16 * 20]);
        if (c + 1 < 25) form(c + 1, p ^ 1);
        acc[0][0] = __builtin_amdgcn_mfma_f32_16x16x32_bf16(af0, bf0, acc[0][0], 0, 0, 0);
        acc[0][1] = __builtin_amdgcn_mfma_f32_16x16x32_bf16(af0, bf1, acc[0][1], 0, 0, 0);
        acc[0][2] = __builtin_amdgcn_mfma_f32_16x16x32_bf16(af0, bf2, acc[0][2], 0, 0, 0);
        acc[1][0] = __builtin_amdgcn_mfma_f32_16x16x32_bf16(af1, bf0, acc[1][0], 0, 0, 0);
        acc[1][1] = __builtin_amdgcn_mfma_f32_16x16x32_bf16(af1, bf1, acc[1][1], 0, 0, 0);
        acc[1][2] = __builtin_amdgcn_mfma_f32_16x16x32_bf16(af1, bf2, acc[1][2], 0, 0, 0);
        __syncthreads();
    }

    // epilogue: C/D layout col(l)=lane&15, row(j)=quad*4+reg
    float bias[3];
    #pragma unroll
    for (int nt = 0; nt < 3; ++nt) {
        int l = nt * 16 + (lane & 15);
        bias[nt] = (l < LL) ? b2[l] : 0.0f;
    }
    const int jr0 = wave * 32 + ((lane >> 4) << 2);
    #pragma unroll
    for (int mt = 0; mt < 2; ++mt) {
        #pragma unroll
        for (int r = 0; r < 4; ++r) {
            int j = jr0 + mt * 16 + r;
            bool msk = avi[j] >= 1;
            size_t rowoff = ((size_t)(b * (TT * TT) + i * TT + j)) * LL;
            #pragma unroll
            for (int nt = 0; nt < 3; ++nt) {
                int l = nt * 16 + (lane & 15);
                if (l < LL) out[rowoff + l] = msk ? (acc[mt][nt][r] + bias[nt]) : 0.0f;
            }
        }
    }
}

// -------- kC: partial exp-sums over positions -> accum[b*40+l] (atomic) --------
__global__ __launch_bounds__(320) void kC(const float* __restrict__ out,
                                          float* __restrict__ accum) {
    const int pc = blockIdx.x;
    const int b  = blockIdx.y;
    const int tid = threadIdx.x;

    const float* base = out + ((size_t)b * (TT * TT) + (size_t)pc * 256) * LL;
    float s = 0.f;
    #pragma unroll 4
    for (int k = 0; k < 32; ++k) {
        s += __expf(base[(size_t)k * 320 + tid]);
    }
    __shared__ float red[320];
    red[tid] = s;
    __syncthreads();
    if (tid < 40) {
        float t = 0.f;
        #pragma unroll
        for (int q = 0; q < 8; ++q) t += red[tid + 40 * q];
        atomicAdd(&accum[b * LL + tid], t);
    }
}

__global__ __launch_bounds__(192) void kC2(const float* __restrict__ accum,
                                           float* __restrict__ lse) {
    int t = threadIdx.x;
    if (t < BB * LL) lse[t] = logf(accum[t]);
}

__global__ __launch_bounds__(256) void kD(float* __restrict__ out,
                                          const float* __restrict__ lse) {
    const int idx = blockIdx.x * 256 + threadIdx.x;
    const int e = idx * 4;
    const int b = e / (TT * TT * LL);
    const int l = e % LL;
    float4 v = ((float4*)out)[idx];
    const float* ls = lse + b * LL + l;
    v.x -= ls[0]; v.y -= ls[1]; v.z -= ls[2]; v.w -= ls[3];
    ((float4*)out)[idx] = v;
}

extern "C" void kernel_launch(void* const* d_in, const int* in_sizes, int n_in,
                              void* d_out, int out_size, void* d_ws, size_t ws_size,
                              hipStream_t stream) {
    const float* hidden = (const float*)d_in[0];
    const float* W1     = (const float*)d_in[1];
    const float* b1     = (const float*)d_in[2];
    const float* W2     = (const float*)d_in[3];
    const float* b2     = (const float*)d_in[4];
    const int*   spans  = (const int*)d_in[5];
    const int*   avail  = (const int*)d_in[6];
    float* out = (float*)d_out;
    float* ws  = (float*)d_ws;

    float*    P     = ws + P_OFF;
    float*    Q     = ws + Q_OFF;
    unsigned* Bfrag = (unsigned*)(ws + BF_OFF);
    float*    accum = ws + ACC_OFF;
    float*    lse   = ws + LSE_OFF;

    kZ <<<dim3(1),        dim3(256), 0, stream>>>(accum);
    kW <<<dim3(19),       dim3(256), 0, stream>>>(W2, Bfrag);
    kA <<<dim3(128, 4),   dim3(256), 0, stream>>>(hidden, W1, b1, P, Q);
    kB <<<dim3(TT, BB),   dim3(256), 0, stream>>>(P, Q, W1, Bfrag, b2, spans, avail, out);
    kC <<<dim3(64, BB),   dim3(320), 0, stream>>>(out, accum);
    kC2<<<dim3(1),        dim3(192), 0, stream>>>(accum, lse);
    kD <<<dim3(2560),     dim3(256), 0, stream>>>(out, lse);
}

// Round 4
// 128.602 us; speedup vs baseline: 3.4390x; 1.3099x over previous
//
#include <hip/hip_runtime.h>
#include <math.h>

#define BB 4
#define TT 128
#define DD 768
#define HD 770
#define HP 800
#define LL 40
#define TP1 129

typedef __attribute__((ext_vector_type(8))) short s16x8;
typedef __attribute__((ext_vector_type(4))) float f32x4;

// ws layout (floats)
#define P_OFF   0
#define Q_OFF   409600
#define W2F_OFF 819200
#define BF1_OFF 838400
#define ACC_OFF 1440512
// total 1440672 floats = 5.77 MB

__device__ __forceinline__ unsigned pkbf(float a, float b) {
    unsigned ua = __float_as_uint(a);
    unsigned ub = __float_as_uint(b);
    return ((ua + 0x8000u) >> 16) | ((ub + 0x8000u) & 0xffff0000u);
}
__device__ __forceinline__ unsigned rne1(float v) {
    unsigned x = __float_as_uint(v);
    return (x + 0x7fffu + ((x >> 16) & 1u)) >> 16;
}

// ================= kPrep: W2-frags | W1-frags | zeroing =================
// blocks [0,19): W2 -> W2f frags (nt 0..2, ks 0..24, lane, 8k)
// blocks [19,607): W1 -> Bf1 frags (half 0..1, nt 0..48, ks 0..23, lane, 8k)
// blocks [607,668): zero accum[160] and Q pad cols [770,800)
__global__ __launch_bounds__(256) void kPrep(const float* __restrict__ W1,
                                             const float* __restrict__ W2,
                                             float* __restrict__ Q,
                                             unsigned* __restrict__ W2f,
                                             unsigned* __restrict__ Bf1,
                                             float* __restrict__ accum) {
    const int bx = blockIdx.x;
    const int tid = threadIdx.x;
    if (bx < 19) {
        int u = bx * 256 + tid;
        if (u >= 4800) return;
        int nt = u / 1600;
        int rem = u - nt * 1600;
        int ks = rem >> 6;
        int lane = rem & 63;
        int kbase = ks * 32 + ((lane >> 4) << 3);
        int l = nt * 16 + (lane & 15);
        unsigned pk[4];
        #pragma unroll
        for (int sp = 0; sp < 4; ++sp) {
            unsigned w[2];
            #pragma unroll
            for (int e = 0; e < 2; ++e) {
                int k = kbase + 2 * sp + e;
                float v = (k < HD && l < LL) ? W2[k * LL + l] : 0.0f;
                w[e] = rne1(v);
            }
            pk[sp] = w[0] | (w[1] << 16);
        }
        ((uint4*)W2f)[u] = make_uint4(pk[0], pk[1], pk[2], pk[3]);
    } else if (bx < 607) {
        int u = (bx - 19) * 256 + tid;         // < 150528
        int lane = u & 63;
        int g = u >> 6;                        // 0..2351
        int ks = g % 24;
        int g2 = g / 24;                       // 0..97
        int nt = g2 % 49;
        int half = g2 / 49;
        int kbase = ks * 32 + ((lane >> 4) << 3);
        int h = nt * 16 + (lane & 15);
        int row0 = half * DD + kbase;
        unsigned pk[4];
        #pragma unroll
        for (int sp = 0; sp < 4; ++sp) {
            unsigned w[2];
            #pragma unroll
            for (int e = 0; e < 2; ++e) {
                float v = (h < HD) ? W1[(size_t)(row0 + 2 * sp + e) * HD + h] : 0.0f;
                w[e] = rne1(v);
            }
            pk[sp] = w[0] | (w[1] << 16);
        }
        ((uint4*)Bf1)[u] = make_uint4(pk[0], pk[1], pk[2], pk[3]);
    } else {
        int u = (bx - 607) * 256 + tid;
        if (u < 160) accum[u] = 0.0f;
        int u2 = u - 160;
        if (u2 >= 0 && u2 < 512 * 30) {
            int row = u2 / 30;
            int h = HD + (u2 - row * 30);
            Q[(size_t)row * HP + h] = 0.0f;
        }
    }
}

// ================= kA: MFMA GEMM X[512x768] @ {W1a,W1b}[768x770] =================
// wave = (mband 0..31, nt 0..48); both halves per wave. 392 blocks x 256.
__global__ __launch_bounds__(256) void kA(const float* __restrict__ hidden,
                                          const unsigned* __restrict__ Bf1,
                                          const float* __restrict__ b1,
                                          float* __restrict__ P,
                                          float* __restrict__ Q) {
    const int tid = threadIdx.x;
    const int w = blockIdx.x * 4 + (tid >> 6);   // 0..1567
    const int lane = tid & 63;
    const int mband = w & 31;
    const int nt = w >> 5;                        // 0..48
    const int b  = mband >> 3;
    const int tt = mband & 7;

    const float* __restrict__ Arow =
        hidden + (size_t)(b * TP1 + 1 + tt * 16 + (lane & 15)) * DD + ((lane >> 4) << 3);
    const uint4* __restrict__ B0 = (const uint4*)Bf1 + ((size_t)nt * 24) * 64 + lane;
    const uint4* __restrict__ B1 = (const uint4*)Bf1 + ((size_t)(49 + nt) * 24) * 64 + lane;

    f32x4 a0 = (f32x4){0.f,0.f,0.f,0.f};
    f32x4 a1 = (f32x4){0.f,0.f,0.f,0.f};

    #pragma unroll 4
    for (int ks = 0; ks < 24; ++ks) {
        float4 x0 = *(const float4*)(Arow + ks * 32);
        float4 x1 = *(const float4*)(Arow + ks * 32 + 4);
        union { unsigned u[4]; s16x8 v; } af;
        af.u[0] = pkbf(x0.x, x0.y); af.u[1] = pkbf(x0.z, x0.w);
        af.u[2] = pkbf(x1.x, x1.y); af.u[3] = pkbf(x1.z, x1.w);
        union { uint4 q; s16x8 v; } bf0, bf1;
        bf0.q = B0[ks * 64];
        bf1.q = B1[ks * 64];
        a0 = __builtin_amdgcn_mfma_f32_16x16x32_bf16(af.v, bf0.v, a0, 0, 0, 0);
        a1 = __builtin_amdgcn_mfma_f32_16x16x32_bf16(af.v, bf1.v, a1, 0, 0, 0);
    }

    const int col = lane & 15;
    const int h = nt * 16 + col;
    if (h < HD) {
        const float bv = b1[h];
        const int quad = lane >> 4;
        #pragma unroll
        for (int r = 0; r < 4; ++r) {
            int t = tt * 16 + quad * 4 + r;
            size_t row = (size_t)(b * TT + t) * HP;
            P[row + h] = a0[r] + bv;
            Q[row + h] = a1[r];
        }
    }
}

// ================= kB: MFMA + fused exp-sum. block=(i,b), 4 waves =================
__global__ __launch_bounds__(256) void kB(const float* __restrict__ P,
                                          const float* __restrict__ Q,
                                          const float* __restrict__ W1,
                                          const unsigned* __restrict__ Bfrag,
                                          const float* __restrict__ b2,
                                          const int* __restrict__ spans,
                                          const int* __restrict__ avail,
                                          float* __restrict__ out,
                                          float* __restrict__ accum) {
    __shared__ unsigned Sb[2][128 * 20];
    __shared__ float var[3 * HP];
    __shared__ int avi[TT];
    __shared__ float sred[192];

    const int i = blockIdx.x;
    const int b = blockIdx.y;
    const int tid = threadIdx.x;
    const int wave = tid >> 6;
    const int lane = tid & 63;

    const int start = spans[b * 2];
    const int end   = spans[b * 2 + 1];

    const int jS = tid >> 1;
    const int hh = (tid & 1) << 4;
    int indS;
    {
        bool isfull = (i == start) && (jS == end);
        bool inside = (start <= i) && (i <= jS) && (jS <= end) && !isfull;
        indS = isfull ? 2 : (inside ? 1 : 0);
    }

    {
        const float* Pi  = P + (size_t)(b * TT + i) * HP;
        const float* w1L = W1 + (size_t)2 * DD * HD;
        for (int h = tid; h < HP; h += 256) {
            float pv = (h < HD) ? Pi[h] : 0.0f;
            float wv = (h < HD) ? w1L[h] : 0.0f;
            var[h]          = pv;
            var[HP + h]     = pv + wv;
            var[2*HP + h]   = pv + wv + wv;
        }
        if (tid < TT) avi[tid] = avail[i * TT + tid];
    }
    __syncthreads();

    const float* Qj = Q + (size_t)(b * TT + jS) * HP;
    const float* vb = var + indS * HP;

    auto form = [&](int c, int p) {
        const int h0 = c * 32 + hh;
        const float4* qp = (const float4*)(Qj + h0);
        float4 q0 = qp[0], q1 = qp[1], q2 = qp[2], q3 = qp[3];
        const float4* vp = (const float4*)(vb + h0);
        float4 v0 = vp[0], v1 = vp[1], v2 = vp[2], v3 = vp[3];
        float s0 = fmaxf(v0.x + q0.x, 0.f), s1 = fmaxf(v0.y + q0.y, 0.f);
        float s2 = fmaxf(v0.z + q0.z, 0.f), s3 = fmaxf(v0.w + q0.w, 0.f);
        float s4 = fmaxf(v1.x + q1.x, 0.f), s5 = fmaxf(v1.y + q1.y, 0.f);
        float s6 = fmaxf(v1.z + q1.z, 0.f), s7 = fmaxf(v1.w + q1.w, 0.f);
        float s8 = fmaxf(v2.x + q2.x, 0.f), s9 = fmaxf(v2.y + q2.y, 0.f);
        float sa = fmaxf(v2.z + q2.z, 0.f), sb_ = fmaxf(v2.w + q2.w, 0.f);
        float sc = fmaxf(v3.x + q3.x, 0.f), sd = fmaxf(v3.y + q3.y, 0.f);
        float se = fmaxf(v3.z + q3.z, 0.f), sf = fmaxf(v3.w + q3.w, 0.f);
        uint4* dst = (uint4*)(&Sb[p][jS * 20 + (hh >> 1)]);
        dst[0] = make_uint4(pkbf(s0,s1), pkbf(s2,s3), pkbf(s4,s5), pkbf(s6,s7));
        dst[1] = make_uint4(pkbf(s8,s9), pkbf(sa,sb_), pkbf(sc,sd), pkbf(se,sf));
    };

    f32x4 acc[2][3];
    #pragma unroll
    for (int mt = 0; mt < 2; ++mt)
        #pragma unroll
        for (int nt = 0; nt < 3; ++nt)
            acc[mt][nt] = (f32x4){0.f, 0.f, 0.f, 0.f};

    form(0, 0);
    __syncthreads();

    const int arow0 = (wave * 32 + (lane & 15)) * 20 + ((lane >> 4) << 2);
    for (int c = 0; c < 25; ++c) {
        const int p = c & 1;
        s16x8 bf0 = *(const s16x8*)(Bfrag + (( 0 + c) * 64 + lane) * 4);
        s16x8 bf1 = *(const s16x8*)(Bfrag + ((25 + c) * 64 + lane) * 4);
        s16x8 bf2 = *(const s16x8*)(Bfrag + ((50 + c) * 64 + lane) * 4);
        s16x8 af0 = *(const s16x8*)(&Sb[p][arow0]);
        s16x8 af1 = *(const s16x8*)(&Sb[p][arow0 + 16 * 20]);
        if (c + 1 < 25) form(c + 1, p ^ 1);
        acc[0][0] = __builtin_amdgcn_mfma_f32_16x16x32_bf16(af0, bf0, acc[0][0], 0, 0, 0);
        acc[0][1] = __builtin_amdgcn_mfma_f32_16x16x32_bf16(af0, bf1, acc[0][1], 0, 0, 0);
        acc[0][2] = __builtin_amdgcn_mfma_f32_16x16x32_bf16(af0, bf2, acc[0][2], 0, 0, 0);
        acc[1][0] = __builtin_amdgcn_mfma_f32_16x16x32_bf16(af1, bf0, acc[1][0], 0, 0, 0);
        acc[1][1] = __builtin_amdgcn_mfma_f32_16x16x32_bf16(af1, bf1, acc[1][1], 0, 0, 0);
        acc[1][2] = __builtin_amdgcn_mfma_f32_16x16x32_bf16(af1, bf2, acc[1][2], 0, 0, 0);
        __syncthreads();
    }

    // epilogue: write out + accumulate exp-sums (replaces old kC)
    float bias[3];
    #pragma unroll
    for (int nt = 0; nt < 3; ++nt) {
        int l = nt * 16 + (lane & 15);
        bias[nt] = (l < LL) ? b2[l] : 0.0f;
    }
    const int jr0 = wave * 32 + ((lane >> 4) << 2);
    float sE[3] = {0.f, 0.f, 0.f};
    #pragma unroll
    for (int mt = 0; mt < 2; ++mt) {
        #pragma unroll
        for (int r = 0; r < 4; ++r) {
            int j = jr0 + mt * 16 + r;
            bool msk = avi[j] >= 1;
            size_t rowoff = ((size_t)(b * (TT * TT) + i * TT + j)) * LL;
            #pragma unroll
            for (int nt = 0; nt < 3; ++nt) {
                int l = nt * 16 + (lane & 15);
                if (l < LL) {
                    float val = msk ? (acc[mt][nt][r] + bias[nt]) : 0.0f;
                    out[rowoff + l] = val;
                    sE[nt] += __expf(val);
                }
            }
        }
    }
    #pragma unroll
    for (int nt = 0; nt < 3; ++nt) {
        float v = sE[nt];
        v += __shfl_xor(v, 16);
        v += __shfl_xor(v, 32);
        if (lane < 16) sred[wave * 48 + nt * 16 + lane] = v;
    }
    __syncthreads();
    if (tid < 48) {
        float t4 = sred[tid] + sred[48 + tid] + sred[96 + tid] + sred[144 + tid];
        if (tid < LL) atomicAdd(&accum[b * LL + tid], t4);
    }
}

// ================= kD: out -= log(accum[b,l]) =================
__global__ __launch_bounds__(256) void kD(float* __restrict__ out,
                                          const float* __restrict__ accum) {
    const int idx = blockIdx.x * 256 + threadIdx.x;
    const int e = idx * 4;
    const int b = e / (TT * TT * LL);
    const int l = e % LL;
    float4 v = ((float4*)out)[idx];
    const float* ac = accum + b * LL + l;
    v.x -= __logf(ac[0]); v.y -= __logf(ac[1]);
    v.z -= __logf(ac[2]); v.w -= __logf(ac[3]);
    ((float4*)out)[idx] = v;
}

extern "C" void kernel_launch(void* const* d_in, const int* in_sizes, int n_in,
                              void* d_out, int out_size, void* d_ws, size_t ws_size,
                              hipStream_t stream) {
    const float* hidden = (const float*)d_in[0];
    const float* W1     = (const float*)d_in[1];
    const float* b1     = (const float*)d_in[2];
    const float* W2     = (const float*)d_in[3];
    const float* b2     = (const float*)d_in[4];
    const int*   spans  = (const int*)d_in[5];
    const int*   avail  = (const int*)d_in[6];
    float* out = (float*)d_out;
    float* ws  = (float*)d_ws;

    float*    P     = ws + P_OFF;
    float*    Q     = ws + Q_OFF;
    unsigned* W2f   = (unsigned*)(ws + W2F_OFF);
    unsigned* Bf1   = (unsigned*)(ws + BF1_OFF);
    float*    accum = ws + ACC_OFF;

    kPrep<<<dim3(668),     dim3(256), 0, stream>>>(W1, W2, Q, W2f, Bf1, accum);
    kA   <<<dim3(392),     dim3(256), 0, stream>>>(hidden, Bf1, b1, P, Q);
    kB   <<<dim3(TT, BB),  dim3(256), 0, stream>>>(P, Q, W1, W2f, b2, spans, avail, out, accum);
    kD   <<<dim3(2560),    dim3(256), 0, stream>>>(out, accum);
}